// Round 2
// baseline (42.898 us; speedup 1.0000x reference)
//
#include <hip/hip_runtime.h>

#define NJ 15
#define FOCALC 575.0f
#define PXC 320.0f
#define PYC 240.0f

constexpr int THREADS = 256;
constexpr int BLOCKS  = 2048;

__device__ __forceinline__ float block_reduce_sum(float val) {
    __shared__ float s[THREADS / 64];
    int lane = threadIdx.x & 63;
    int wid  = threadIdx.x >> 6;
    #pragma unroll
    for (int off = 32; off > 0; off >>= 1)
        val += __shfl_down(val, off, 64);
    if (lane == 0) s[wid] = val;
    __syncthreads();
    if (wid == 0) {
        val = (lane < (THREADS / 64)) ? s[lane] : 0.0f;
        #pragma unroll
        for (int off = (THREADS / 128); off > 0; off >>= 1)
            val += __shfl_down(val, off, 64);
    }
    return val;  // valid in thread 0
}

__global__ __launch_bounds__(THREADS) void proj_partial_kernel(
        const float* __restrict__ pose3d,   // [3][15]
        const float* __restrict__ bone2d,   // [N][2][15]
        const float* __restrict__ R,        // [N][3][3]
        const float* __restrict__ C,        // [N][3]
        float* __restrict__ partial,        // [BLOCKS]
        int N) {
    __shared__ float p3d[3 * NJ];
    if (threadIdx.x < 3 * NJ) p3d[threadIdx.x] = pose3d[threadIdx.x];
    __syncthreads();

    float acc = 0.0f;
    for (int n = blockIdx.x * blockDim.x + threadIdx.x; n < N;
         n += gridDim.x * blockDim.x) {
        const float* Rp = R + 9 * (long)n;
        float r0 = Rp[0], r1 = Rp[1], r2 = Rp[2];
        float r3 = Rp[3], r4 = Rp[4], r5 = Rp[5];
        float r6 = Rp[6], r7 = Rp[7], r8 = Rp[8];
        const float* Cp = C + 3 * (long)n;
        float c0 = Cp[0], c1 = Cp[1], c2 = Cp[2];

        // bone2d: 30 floats/frame, frame offset 120 B -> 8 B aligned, load as float2
        const float2* b2 = (const float2*)(bone2d + 30 * (long)n);
        float bj[30];
        #pragma unroll
        for (int t = 0; t < 15; ++t) {
            float2 w = b2[t];
            bj[2 * t]     = w.x;
            bj[2 * t + 1] = w.y;
        }

        float fs = 0.0f;
        #pragma unroll
        for (int j = 0; j < NJ; ++j) {
            float x0 = p3d[j] - c0;
            float x1 = p3d[NJ + j] - c1;
            float x2 = p3d[2 * NJ + j] - c2;
            // P_cam[c] = sum_k R[k][c] * X[k]   (einsum 'nkc,nkj->ncj')
            float pc0 = r0 * x0 + r3 * x1 + r6 * x2;
            float pc1 = r1 * x0 + r4 * x1 + r7 * x2;
            float pc2 = r2 * x0 + r5 * x1 + r8 * x2;
            float u = FOCALC * pc0 / pc2 + PXC;
            float v = FOCALC * pc1 / pc2 + PYC;
            float du = u - bj[j];
            float dv = v - bj[NJ + j];
            fs += du * du + dv * dv;
        }
        acc += fs / 30.0f;   // per-frame MSE
    }

    float bsum = block_reduce_sum(acc);
    if (threadIdx.x == 0) partial[blockIdx.x] = bsum;
}

__global__ __launch_bounds__(THREADS) void finalize_kernel(
        const float* __restrict__ partial,
        const float* __restrict__ pose3d,
        float* __restrict__ out,
        int nPartial) {
    float acc = 0.0f;
    for (int i = threadIdx.x; i < nPartial; i += blockDim.x)
        acc += partial[i];
    acc = block_reduce_sum(acc);
    if (threadIdx.x == 0) {
        // symmetry loss (bone indices are compile-time constants in reference)
        const int lb[6][2] = {{0,1},{1,2},{2,3},{8,9},{9,10},{10,11}};
        const int rb[6][2] = {{0,4},{4,5},{5,6},{8,12},{12,13},{13,14}};
        float sym = 0.0f;
        #pragma unroll
        for (int bb = 0; bb < 6; ++bb) {
            float ll = 0.0f, lr = 0.0f;
            #pragma unroll
            for (int k = 0; k < 3; ++k) {
                float dl = pose3d[k * NJ + lb[bb][0]] - pose3d[k * NJ + lb[bb][1]];
                float dr = pose3d[k * NJ + rb[bb][0]] - pose3d[k * NJ + rb[bb][1]];
                ll += dl * dl;
                lr += dr * dr;
            }
            float d = ll - lr;
            sym += d * d;
        }
        sym /= 6.0f;
        out[0] = 1.0f * sym + 1.0f * acc;
    }
}

extern "C" void kernel_launch(void* const* d_in, const int* in_sizes, int n_in,
                              void* d_out, int out_size, void* d_ws, size_t ws_size,
                              hipStream_t stream) {
    const float* pose3d = (const float*)d_in[0];
    const float* bone2d = (const float*)d_in[1];
    const float* R      = (const float*)d_in[2];
    const float* C      = (const float*)d_in[3];
    float* out = (float*)d_out;
    float* partial = (float*)d_ws;

    int N = in_sizes[3] / 3;  // C_drone has N*3 elements

    proj_partial_kernel<<<BLOCKS, THREADS, 0, stream>>>(pose3d, bone2d, R, C, partial, N);
    finalize_kernel<<<1, THREADS, 0, stream>>>(partial, pose3d, out, BLOCKS);
}